// Round 8
// baseline (592.635 us; speedup 1.0000x reference)
//
#include <hip/hip_runtime.h>
#include <hip/hip_bf16.h>
#include <math.h>

#define B_ 2
#define L_ 2048
#define D_ 1024
#define H_ 4
#define NC 64   // chunks per sequence

typedef unsigned short ushort_t;
typedef __bf16 bf16x8 __attribute__((ext_vector_type(8)));
typedef float f32x4 __attribute__((ext_vector_type(4)));
typedef ushort_t u16x8 __attribute__((ext_vector_type(8)));

__device__ __forceinline__ ushort_t f2bs(float f) {
    __hip_bfloat16 h = __float2bfloat16(f);
    ushort_t u;
    __builtin_memcpy(&u, &h, 2);
    return u;
}
__device__ __forceinline__ float bs2f(ushort_t u) {
    unsigned int v = ((unsigned int)u) << 16;
    float f;
    __builtin_memcpy(&f, &v, 4);
    return f;
}
__device__ __forceinline__ void stor(float* p, float v) { *p = v; }
__device__ __forceinline__ void stor(ushort_t* p, float v) { *p = f2bs(v); }

__device__ __forceinline__ float wred(float v) {
    v += __shfl_down(v, 32);
    v += __shfl_down(v, 16);
    v += __shfl_down(v, 8);
    v += __shfl_down(v, 4);
    v += __shfl_down(v, 2);
    v += __shfl_down(v, 1);
    return v;
}

__device__ __forceinline__ void gload16(const void* g, void* l) {
    __builtin_amdgcn_global_load_lds((const __attribute__((address_space(1))) void*)g,
                                     (__attribute__((address_space(3))) void*)l, 16, 0, 0);
}

// raw barrier: drain LDS only, leave vmcnt (global loads) in flight
#define LGKM0_BAR()                                          \
    do {                                                     \
        asm volatile("s_waitcnt lgkmcnt(0)" ::: "memory");   \
        __builtin_amdgcn_s_barrier();                        \
    } while (0)

// ---------------- 4-way transpose+cast: W[1024][1024] f32 -> WT[1024][1024] bf16
__global__ __launch_bounds__(256) void tcast4_k(const float* __restrict__ s0,
                                                const float* __restrict__ s1,
                                                const float* __restrict__ s2,
                                                const float* __restrict__ s3,
                                                ushort_t* __restrict__ d0,
                                                ushort_t* __restrict__ d1,
                                                ushort_t* __restrict__ d2,
                                                ushort_t* __restrict__ d3) {
    __shared__ float tile[32 * 33];
    const int z = blockIdx.z;
    const float* W = (z == 0) ? s0 : (z == 1) ? s1 : (z == 2) ? s2 : s3;
    ushort_t* WT = (z == 0) ? d0 : (z == 1) ? d1 : (z == 2) ? d2 : d3;
    const int k0 = blockIdx.y << 5, n0 = blockIdx.x << 5;
    for (int e = threadIdx.x; e < 1024; e += 256)
        tile[(e >> 5) * 33 + (e & 31)] = W[(size_t)(k0 + (e >> 5)) * 1024 + n0 + (e & 31)];
    __syncthreads();
    for (int e = threadIdx.x; e < 1024; e += 256)
        WT[(size_t)(n0 + (e >> 5)) * 1024 + k0 + (e & 31)] =
            f2bs(tile[(e & 31) * 33 + (e >> 5)]);
}

// ------------------------------------------- transpose+cast (generic dims)
__global__ __launch_bounds__(256) void tcast_k(const float* __restrict__ W,
                                               ushort_t* __restrict__ WT, int K, int N) {
    __shared__ float tile[32 * 33];
    const int k0 = blockIdx.y << 5, n0 = blockIdx.x << 5;
    for (int e = threadIdx.x; e < 1024; e += 256)
        tile[(e >> 5) * 33 + (e & 31)] = W[(size_t)(k0 + (e >> 5)) * N + n0 + (e & 31)];
    __syncthreads();
    for (int e = threadIdx.x; e < 1024; e += 256)
        WT[(size_t)(n0 + (e >> 5)) * K + k0 + (e & 31)] = f2bs(tile[(e & 31) * 33 + (e >> 5)]);
}

// ------------------------------------------- bf16 MFMA GEMM (TN): C = act(A @ Bt^T + bias)
template <int ACT, typename OT>
__global__ __launch_bounds__(256) void gemm_bf(const ushort_t* __restrict__ A,
                                               const ushort_t* __restrict__ Bt,
                                               const float* __restrict__ bias,
                                               OT* __restrict__ C,
                                               int M, int N, int K) {
    __shared__ ushort_t As[128 * 32];
    __shared__ ushort_t Bs[128 * 32];
    const int t = threadIdx.x;
    const int wv = t >> 6, l = t & 63;
    const int m0 = blockIdx.y << 7, n0 = blockIdx.x << 7;
    const int wm = wv & 1, wn = wv >> 1;
    const int q4 = l >> 4, c16 = l & 15;
    f32x4 acc[4][4];
#pragma unroll
    for (int i = 0; i < 4; ++i)
#pragma unroll
        for (int j = 0; j < 4; ++j) {
            f32x4 z = {0.f, 0.f, 0.f, 0.f};
            acc[i][j] = z;
        }
    const int srow = (l >> 2);
    const int scol = (l & 3) << 3;
    for (int k0 = 0; k0 < K; k0 += 32) {
        __syncthreads();
#pragma unroll
        for (int si = 0; si < 2; ++si) {
            const int s = wv * 2 + si;
            gload16(&A[(size_t)(m0 + s * 16 + srow) * K + k0 + scol], &As[s * 512]);
            gload16(&Bt[(size_t)(n0 + s * 16 + srow) * K + k0 + scol], &Bs[s * 512]);
        }
        __syncthreads();
        bf16x8 af[4], bff[4];
#pragma unroll
        for (int mi = 0; mi < 4; ++mi)
            af[mi] = *(const bf16x8*)&As[(wm * 64 + mi * 16 + c16) * 32 + q4 * 8];
#pragma unroll
        for (int ni = 0; ni < 4; ++ni)
            bff[ni] = *(const bf16x8*)&Bs[(wn * 64 + ni * 16 + c16) * 32 + q4 * 8];
#pragma unroll
        for (int mi = 0; mi < 4; ++mi)
#pragma unroll
            for (int ni = 0; ni < 4; ++ni)
                acc[mi][ni] = __builtin_amdgcn_mfma_f32_16x16x32_bf16(af[mi], bff[ni],
                                                                     acc[mi][ni], 0, 0, 0);
    }
#pragma unroll
    for (int mi = 0; mi < 4; ++mi)
#pragma unroll
        for (int ni = 0; ni < 4; ++ni)
#pragma unroll
            for (int r = 0; r < 4; ++r) {
                const int row = m0 + wm * 64 + mi * 16 + q4 * 4 + r;
                const int col = n0 + wn * 64 + ni * 16 + c16;
                float v = acc[mi][ni][r];
                if (ACT == 1) {
                    v += bias[col];
                    v = 0.5f * v * (1.0f + erff(v * 0.70710678118654752f));
                }
                stor(&C[(size_t)row * N + col], v);
            }
}

// ---------------- fused causal conv(K=4) + silu (+ row l2norm), LDS-tiled
// X row stride 3072 (qkv fused buffer); one block = (b, 32 l-rows, head)
template <int DO_NORM>
__global__ __launch_bounds__(256) void convql_k(const float* __restrict__ X,
                                                const float* __restrict__ cw,
                                                ushort_t* __restrict__ Ybf) {
    __shared__ float xs[35 * 256];
    const int bid = blockIdx.x;
    const int h = bid & 3, lt = (bid >> 2) & 63, b = bid >> 8;
    const int t = threadIdx.x;
    const int l0 = lt << 5;
    const int cg = (h << 8) | t;
    for (int e = t; e < 35 * 256; e += 256) {
        const int r = e >> 8, c = e & 255;
        const int gl = l0 + r - 3;
        xs[e] = (gl >= 0) ? X[((size_t)(b * L_) + gl) * 3072 + (h << 8) + c] : 0.f;
    }
    const float w0 = cw[cg * 4 + 0], w1 = cw[cg * 4 + 1];
    const float w2 = cw[cg * 4 + 2], w3 = cw[cg * 4 + 3];
    __syncthreads();
    float yr[32];
#pragma unroll
    for (int l = 0; l < 32; ++l) {
        const float a = xs[(l + 0) * 256 + t] * w0 + xs[(l + 1) * 256 + t] * w1 +
                        xs[(l + 2) * 256 + t] * w2 + xs[(l + 3) * 256 + t] * w3;
        yr[l] = a / (1.f + expf(-a));
    }
    if (DO_NORM) {
        __syncthreads();
#pragma unroll
        for (int l = 0; l < 32; ++l) xs[l * 256 + t] = yr[l];
        __syncthreads();
        const int wv = t >> 6, lane = t & 63;
#pragma unroll
        for (int ri = 0; ri < 8; ++ri) {
            const int r = wv * 8 + ri;
            float4 v = *(float4*)&xs[r * 256 + lane * 4];
            float ss = v.x * v.x + v.y * v.y + v.z * v.z + v.w * v.w;
            ss = wred(ss);
            ss = __shfl(ss, 0);
            const float s = rsqrtf(ss + 1e-6f);
            const size_t go = ((size_t)(b * L_) + l0 + r) * 1024 + (h << 8) + lane * 4;
            ushort4 p;
            p.x = f2bs(v.x * s); p.y = f2bs(v.y * s);
            p.z = f2bs(v.z * s); p.w = f2bs(v.w * s);
            *(ushort4*)&Ybf[go] = p;
        }
    } else {
#pragma unroll
        for (int l = 0; l < 32; ++l)
            Ybf[((size_t)(b * L_) + l0 + l) * 1024 + cg] = f2bs(yr[l]);
    }
}

// ---------------- fused FIR branches (K=1,3,7,31), bf16 in/out, LDS-tiled
__global__ __launch_bounds__(256) void fir_k(const ushort_t* __restrict__ V,
                                             const float* __restrict__ w1w,
                                             const float* __restrict__ w3w,
                                             const float* __restrict__ w7w,
                                             const float* __restrict__ w31w,
                                             ushort_t* __restrict__ o1,
                                             ushort_t* __restrict__ o3,
                                             ushort_t* __restrict__ o7,
                                             ushort_t* __restrict__ o31) {
    __shared__ float xs[62 * 256];
    const int bid = blockIdx.x;
    const int h = bid & 3, lt = (bid >> 2) & 63, b = bid >> 8;
    const int t = threadIdx.x;
    const int l0 = lt << 5;
    const int cg = (h << 8) | t;
    for (int e = t; e < 62 * 256; e += 256) {
        const int r = e >> 8, c = e & 255;
        const int gl = l0 + r - 30;
        xs[e] = (gl >= 0) ? bs2f(V[((size_t)(b * L_) + gl) * 1024 + (h << 8) + c]) : 0.f;
    }
    float lw31[31], lw7[7], lw3[3];
#pragma unroll
    for (int j = 0; j < 31; ++j) lw31[j] = w31w[cg * 31 + j];
#pragma unroll
    for (int j = 0; j < 7; ++j) lw7[j] = w7w[cg * 7 + j];
#pragma unroll
    for (int j = 0; j < 3; ++j) lw3[j] = w3w[cg * 3 + j];
    const float lw1 = w1w[cg];
    __syncthreads();
    for (int l = 0; l < 32; ++l) {
        float a31 = 0.f, a7 = 0.f, a3 = 0.f, v = 0.f;
#pragma unroll
        for (int j = 0; j < 31; ++j) {
            v = xs[(l + j) * 256 + t];
            a31 += v * lw31[j];
            if (j >= 24) a7 += v * lw7[j - 24];
            if (j >= 28) a3 += v * lw3[j - 28];
        }
        const size_t go = ((size_t)(b * L_) + l0 + l) * 1024 + cg;
        o31[go] = f2bs(a31);
        o7[go] = f2bs(a7);
        o3[go] = f2bs(a3);
        o1[go] = f2bs(v * lw1);
    }
}

// ------------- beta = sigmoid(hs @ b_w); emit gate_in hs-part + hs_bf (bf16)
__global__ __launch_bounds__(64) void beta_k(const float* __restrict__ hs,
                                             const float* __restrict__ bw,
                                             float* __restrict__ beta,
                                             ushort_t* __restrict__ gin,
                                             ushort_t* __restrict__ hsbf) {
    const int row = blockIdx.x;
    const int lane = threadIdx.x;
    float a0 = 0, a1 = 0, a2 = 0, a3 = 0;
    const float* hp = hs + (size_t)row * D_;
    ushort_t* gp = gin + (size_t)row * 1120;
    ushort_t* hb = hsbf + (size_t)row * D_;
    for (int c = lane; c < D_; c += 64) {
        const float x = hp[c];
        const ushort_t xb = f2bs(x);
        gp[c] = xb;
        hb[c] = xb;
        a0 += x * bw[c * 4 + 0];
        a1 += x * bw[c * 4 + 1];
        a2 += x * bw[c * 4 + 2];
        a3 += x * bw[c * 4 + 3];
    }
    a0 = wred(a0); a1 = wred(a1); a2 = wred(a2); a3 = wred(a3);
    if (lane == 0) {
        float* o = beta + (size_t)row * 4;
        o[0] = 1.f / (1.f + expf(-a0));
        o[1] = 1.f / (1.f + expf(-a1));
        o[2] = 1.f / (1.f + expf(-a2));
        o[3] = 1.f / (1.f + expf(-a3));
    }
}

// --------------- fused MFMA delta-prep (bf16 v input). Exports scan operands in
// MFMA-fragment-linear layouts.
__global__ __launch_bounds__(256) void prep2_k(const ushort_t* __restrict__ qbf,
                                               const ushort_t* __restrict__ kbf,
                                               const ushort_t* __restrict__ vbf,
                                               const float* __restrict__ beta,
                                               ushort_t* __restrict__ qfr,
                                               ushort_t* __restrict__ wfr,
                                               float* __restrict__ ufr,
                                               ushort_t* __restrict__ atfr,
                                               ushort_t* __restrict__ ktfr) {
    __shared__ ushort_t w_s[32 * 264];     // w staging (written late)
    __shared__ ushort_t kT_lds[256 * 32];  // swizzled: seg s at (s ^ ((c>>1)&3))
    __shared__ ushort_t vT_lds[256 * 32];  // same swizzle
    __shared__ float Am[32 * 33];
    __shared__ float Tm[32 * 33];
    __shared__ ushort_t Tb[32 * 40];       // T' bf16
    __shared__ ushort_t at_s[32 * 40];     // attn bf16
    __shared__ float beta_s[32];
    const int bid = blockIdx.x;  // bh*NC + ci
    const int bh = bid >> 6, ci = bid & 63;
    const int b = bh >> 2, h = bh & 3;
    const int t = threadIdx.x;
    const int wv = t >> 6, lane = t & 63;
    const int mi = wv & 1, ni = wv >> 1;
    const int l16 = lane & 15, quad = lane >> 4;
    const size_t cb = (size_t)bid;
    const size_t grow = ((size_t)(b * L_ + ci * 32)) * 1024 + (h << 8);
    const f32x4 z4 = {0.f, 0.f, 0.f, 0.f};

    if (t < 32) beta_s[t] = beta[(size_t)(b * L_ + ci * 32 + t) * 4 + h];
    // build kT/vT (bf16, swizzled) straight from global
#pragma unroll
    for (int j = 0; j < 4; ++j) {
        const int idx = j * 2048 + t * 8, r = idx >> 8, c = idx & 255;
        const u16x8 kv = *(const u16x8*)&kbf[grow + (size_t)r * 1024 + c];
        const u16x8 vv = *(const u16x8*)&vbf[grow + (size_t)r * 1024 + c];
#pragma unroll
        for (int x = 0; x < 8; ++x) {
            const int cc = c + x;
            const int sp = (r >> 3) ^ ((cc >> 1) & 3);
            kT_lds[cc * 32 + sp * 8 + (r & 7)] = kv[x];
            vT_lds[cc * 32 + sp * 8 + (r & 7)] = vv[x];
        }
    }
    // G = k@kT and attn = q@kT from global register fragments; waves 0,1 export qfr
    f32x4 g = z4, atv = z4;
#pragma unroll
    for (int s = 0; s < 8; ++s) {
        const bf16x8 a =
            *(const bf16x8*)&kbf[grow + (size_t)(mi * 16 + l16) * 1024 + s * 32 + (quad << 3)];
        const bf16x8 bb =
            *(const bf16x8*)&kbf[grow + (size_t)(ni * 16 + l16) * 1024 + s * 32 + (quad << 3)];
        const bf16x8 qa =
            *(const bf16x8*)&qbf[grow + (size_t)(mi * 16 + l16) * 1024 + s * 32 + (quad << 3)];
        g = __builtin_amdgcn_mfma_f32_16x16x32_bf16(a, bb, g, 0, 0, 0);
        atv = __builtin_amdgcn_mfma_f32_16x16x32_bf16(qa, bb, atv, 0, 0, 0);
        if (ni == 0) *(bf16x8*)&qfr[((cb * 2 + mi) * 8 + s) * 512 + lane * 8] = qa;
    }
    __syncthreads();  // beta_s + kT + vT visible
    // Am / Tm init + attn -> at_s; ktfr export
#pragma unroll
    for (int r = 0; r < 4; ++r) {
        const int row = mi * 16 + (quad << 2) + r;
        const int col = ni * 16 + l16;
        Am[row * 33 + col] = (col < row) ? -beta_s[row] * g[r] : 0.f;
        Tm[row * 33 + col] = (row == col) ? 1.f : 0.f;
        at_s[row * 40 + col] = (col <= row) ? f2bs(atv[r]) : (ushort_t)0;
    }
#pragma unroll
    for (int j2 = 0; j2 < 4; ++j2) {
        const int tc = wv * 4 + j2;
        const int c = tc * 16 + l16;
        const int sp = quad ^ ((c >> 1) & 3);
        *(u16x8*)&ktfr[(cb * 16 + tc) * 512 + lane * 8] = *(const u16x8*)&kT_lds[c * 32 + sp * 8];
    }
    __syncthreads();  // Am/Tm/at_s visible
    if (wv < 2) {
        const u16x8 av = *(const u16x8*)&at_s[(wv * 16 + l16) * 40 + (quad << 3)];
        *(u16x8*)&atfr[(cb * 2 + wv) * 512 + lane * 8] = av;
    }
    // forward substitution: T[i] += sum_{j<i} A[i][j] T[j]
    for (int i = 1; i < 32; ++i) {
        if (t < 32) {
            float s = 0.f;
            for (int j = 0; j < i; ++j) s += Am[i * 33 + j] * Tm[j * 33 + t];
            Tm[i * 33 + t] += s;
        }
        __syncthreads();
    }
    // Tb = bf16(T * beta_col)
#pragma unroll
    for (int j = 0; j < 4; ++j) {
        const int e = j * 256 + t, i = e >> 5, jj = e & 31;
        Tb[i * 40 + jj] = f2bs(Tm[i * 33 + jj] * beta_s[jj]);
    }
    __syncthreads();
    // w = T'@k -> w_s; u = T'@v -> ufr (fragment layout direct)
    const bf16x8 tf = *(const bf16x8*)&Tb[(mi * 16 + l16) * 40 + (quad << 3)];
#pragma unroll
    for (int j = 0; j < 8; ++j) {
        const int nt = ni * 8 + j;
        const int d = (nt << 4) + l16;
        const int sp = quad ^ ((d >> 1) & 3);
        const bf16x8 kb = *(const bf16x8*)&kT_lds[d * 32 + (sp << 3)];
        const bf16x8 vb = *(const bf16x8*)&vT_lds[d * 32 + (sp << 3)];
        const f32x4 wacc = __builtin_amdgcn_mfma_f32_16x16x32_bf16(tf, kb, z4, 0, 0, 0);
        const f32x4 uacc = __builtin_amdgcn_mfma_f32_16x16x32_bf16(tf, vb, z4, 0, 0, 0);
        *(float4*)&ufr[((cb * 16 + nt) * 2 + mi) * 256 + lane * 4] =
            make_float4(uacc[0], uacc[1], uacc[2], uacc[3]);
#pragma unroll
        for (int r = 0; r < 4; ++r) {
            const int row = mi * 16 + (quad << 2) + r;
            w_s[row * 264 + d] = f2bs(wacc[r]);
        }
    }
    __syncthreads();
    // export wfr (waves 0,1)
    if (wv < 2) {
#pragma unroll
        for (int s = 0; s < 8; ++s) {
            const u16x8 wv8 = *(const u16x8*)&w_s[(wv * 16 + l16) * 264 + s * 32 + (quad << 3)];
            *(u16x8*)&wfr[((cb * 2 + wv) * 8 + s) * 512 + lane * 8] = wv8;
        }
    }
}

// ---------------------- MFMA scan: fragment-linear coalesced loads, reg double-buffer,
// S-mirror double-buffered in LDS (2 lgkm-only barriers/chunk); bf16 dlt out
__global__ __launch_bounds__(256, 1) void scan5_k(const ushort_t* __restrict__ qfr,
                                                  const ushort_t* __restrict__ wfr,
                                                  const float* __restrict__ ufr,
                                                  const ushort_t* __restrict__ atfr,
                                                  const ushort_t* __restrict__ ktfr,
                                                  ushort_t* __restrict__ dlt) {
    __shared__ ushort_t uh_lds[16 * 40];
    __shared__ ushort_t S_lds[2][16 * 264];
    const int t = threadIdx.x;
    const int wv = t >> 6, lane = t & 63;
    const int bh = blockIdx.x & 7, tile = blockIdx.x >> 3;
    const int b = bh >> 2, h = bh & 3;
    const int l16 = lane & 15, quad = lane >> 4;
    for (int e = t; e < 16 * 264; e += 256) S_lds[0][e] = 0;

    f32x4 Sacc[8];
#pragma unroll
    for (int j = 0; j < 8; ++j) {
        f32x4 z = {0.f, 0.f, 0.f, 0.f};
        Sacc[j] = z;
    }

    bf16x8 wfA[8], qfA[8], atfA, ktA[8];
    bf16x8 wfB[8], qfB[8], atfB, ktB[8];
    float uvA[4], uvB[4];

    auto loadf = [&](int ci, bf16x8* wf, bf16x8* qf, bf16x8& atf, float* uv, bf16x8* ktf) {
        const size_t cb = (size_t)(bh * NC + ci);
        if (wv < 2) {
            const ushort_t* wsrc = wfr + (cb * 2 + wv) * 8 * 512;
            const ushort_t* qsrc = qfr + (cb * 2 + wv) * 8 * 512;
#pragma unroll
            for (int s = 0; s < 8; ++s) {
                wf[s] = *(const bf16x8*)&wsrc[s * 512 + lane * 8];
                qf[s] = *(const bf16x8*)&qsrc[s * 512 + lane * 8];
            }
            atf = *(const bf16x8*)&atfr[(cb * 2 + wv) * 512 + lane * 8];
            const float4 u4 = *(const float4*)&ufr[((cb * 16 + tile) * 2 + wv) * 256 + lane * 4];
            uv[0] = u4.x; uv[1] = u4.y; uv[2] = u4.z; uv[3] = u4.w;
        } else {
            const ushort_t* ksrc = ktfr + cb * 16 * 512;
#pragma unroll
            for (int j = 0; j < 8; ++j) {
                const int tc = ((wv - 2) << 3) + j;
                ktf[j] = *(const bf16x8*)&ksrc[tc * 512 + lane * 8];
            }
        }
    };
    auto sfrag = [&](int p, int k0) -> bf16x8 {
        return *(const bf16x8*)&S_lds[p][l16 * 264 + k0 + (quad << 3)];
    };
    auto uhfrag = [&]() -> bf16x8 {
        return *(const bf16x8*)&uh_lds[l16 * 40 + (quad << 3)];
    };
    auto compute = [&](int ci, bf16x8* wf, bf16x8* qf, bf16x8& atf, float* uv, bf16x8* ktf) {
        const int p = ci & 1;
        const size_t gbase = ((size_t)(b * L_ + ci * 32)) * D_ + (h << 8);
        if (wv < 2) {
            f32x4 a[4];
#pragma unroll
            for (int j = 0; j < 4; ++j) {
                f32x4 z = {0.f, 0.f, 0.f, 0.f};
                a[j] = z;
            }
#pragma unroll
            for (int s = 0; s < 8; ++s)
                a[s & 3] = __builtin_amdgcn_mfma_f32_16x16x32_bf16(wf[s], sfrag(p, s * 32),
                                                                   a[s & 3], 0, 0, 0);
            ushort4 up;
            up.x = f2bs(uv[0] - a[0][0] - a[1][0] - a[2][0] - a[3][0]);
            up.y = f2bs(uv[1] - a[0][1] - a[1][1] - a[2][1] - a[3][1]);
            up.z = f2bs(uv[2] - a[0][2] - a[1][2] - a[2][2] - a[3][2]);
            up.w = f2bs(uv[3] - a[0][3] - a[1][3] - a[2][3] - a[3][3]);
            *(ushort4*)&uh_lds[l16 * 40 + (wv << 4) + (quad << 2)] = up;
        }
        LGKM0_BAR();  // uh visible
        if (wv < 2) {
            f32x4 o[4];
#pragma unroll
            for (int j = 0; j < 4; ++j) {
                f32x4 z = {0.f, 0.f, 0.f, 0.f};
                o[j] = z;
            }
#pragma unroll
            for (int s = 0; s < 8; ++s)
                o[s & 3] = __builtin_amdgcn_mfma_f32_16x16x32_bf16(qf[s], sfrag(p, s * 32),
                                                                   o[s & 3], 0, 0, 0);
            o[0] = __builtin_amdgcn_mfma_f32_16x16x32_bf16(atf, uhfrag(), o[0], 0, 0, 0);
#pragma unroll
            for (int r = 0; r < 4; ++r)
                dlt[gbase + (size_t)((wv << 4) + (quad << 2) + r) * D_ + (tile << 4) + l16] =
                    f2bs(o[0][r] + o[1][r] + o[2][r] + o[3][r]);
        } else {
            const bf16x8 uf = uhfrag();
#pragma unroll
            for (int j = 0; j < 8; ++j)
                Sacc[j] = __builtin_amdgcn_mfma_f32_16x16x32_bf16(ktf[j], uf, Sacc[j], 0, 0, 0);
#pragma unroll
            for (int j = 0; j < 8; ++j) {
                const int c0 = ((((wv - 2) << 3) + j) << 4) + (quad << 2);
                ushort4 pk;
                pk.x = f2bs(Sacc[j][0]);
                pk.y = f2bs(Sacc[j][1]);
                pk.z = f2bs(Sacc[j][2]);
                pk.w = f2bs(Sacc[j][3]);
                *(ushort4*)&S_lds[p ^ 1][l16 * 264 + c0] = pk;
            }
        }
        LGKM0_BAR();  // mirror ready; uh free for next chunk
    };

    loadf(0, wfA, qfA, atfA, uvA, ktA);
    LGKM0_BAR();  // S zero-init visible
    for (int ci = 0; ci < NC; ci += 2) {
        loadf(ci + 1, wfB, qfB, atfB, uvB, ktB);
        compute(ci, wfA, qfA, atfA, uvA, ktA);
        if (ci + 2 < NC) loadf(ci + 2, wfA, qfA, atfA, uvA, ktA);
        compute(ci + 1, wfB, qfB, atfB, uvB, ktB);
    }
}

// ---------------- branch stats (bf16 in) -> gate_in stat columns (bf16); 4 rows/block
__global__ __launch_bounds__(256) void stats_k(const ushort_t* __restrict__ f1,
                                               const ushort_t* __restrict__ f3,
                                               const ushort_t* __restrict__ f7,
                                               const ushort_t* __restrict__ f31,
                                               const ushort_t* __restrict__ dl,
                                               const ushort_t* __restrict__ vv,
                                               ushort_t* __restrict__ gin) {
    const int wv = threadIdx.x >> 6, lane = threadIdx.x & 63;
    const int row = blockIdx.x * 4 + wv;  // (b*L+l)*H + h
    const ushort_t* ptrs[6] = {f1, f3, f7, f31, dl, vv};
    const size_t base = (size_t)row * 256 + lane * 4;
    ushort_t* gp = gin + (size_t)(row >> 2) * 1120 + 1024 + (row & 3) * 24;
    for (int br = 0; br < 6; ++br) {
        const ushort4 xb = *(const ushort4*)&ptrs[br][base];
        const float x0 = bs2f(xb.x), x1 = bs2f(xb.y), x2 = bs2f(xb.z), x3 = bs2f(xb.w);
        float s1 = x0 + x1 + x2 + x3;
        float s2 = x0 * x0 + x1 * x1 + x2 * x2 + x3 * x3;
        float sa = fabsf(x0) + fabsf(x1) + fabsf(x2) + fabsf(x3);
        s1 = wred(s1); s2 = wred(s2); sa = wred(sa);
        if (lane == 0) {
            const float m = s1 / 256.f;
            float var = (s2 - 256.f * m * m) / 255.f;
            if (var < 0.f) var = 0.f;
            gp[br * 4 + 0] = f2bs(m);
            gp[br * 4 + 1] = f2bs(sqrtf(var));
            gp[br * 4 + 2] = f2bs(sa / 256.f);
            gp[br * 4 + 3] = f2bs(sqrtf(s2));
        }
    }
}

// ---------------------------------------------- logits -> softmax weights (bf16 hgate)
__global__ __launch_bounds__(256) void wts_k(const ushort_t* __restrict__ hg,
                                             const float* __restrict__ w2,
                                             const float* __restrict__ b2,
                                             const float* __restrict__ glt,
                                             float* __restrict__ wts) {
    const int row = blockIdx.x;
    const int h = threadIdx.x >> 6, lane = threadIdx.x & 63;
    float hv[16];
    const ushort_t* hp = hg + (size_t)row * 1024;
#pragma unroll
    for (int ii = 0; ii < 16; ++ii) hv[ii] = bs2f(hp[lane + 64 * ii]);
    float lg[6];
#pragma unroll
    for (int s = 0; s < 6; ++s) {
        const int j = h * 6 + s;
        float acc = 0.f;
#pragma unroll
        for (int ii = 0; ii < 16; ++ii) acc += hv[ii] * w2[(size_t)(lane + 64 * ii) * 24 + j];
        lg[s] = wred(acc);
    }
    if (lane == 0) {
        const float temp = log1pf(expf(glt[h])) + 0.5f;
        float mx = -1e30f;
#pragma unroll
        for (int s = 0; s < 6; ++s) {
            lg[s] = (lg[s] + b2[h * 6 + s]) / temp;
            mx = fmaxf(mx, lg[s]);
        }
        float se = 0.f;
#pragma unroll
        for (int s = 0; s < 6; ++s) {
            lg[s] = expf(lg[s] - mx);
            se += lg[s];
        }
        float* o = &wts[(size_t)row * 24 + h * 6];
        const float inv = 1.f / se;
#pragma unroll
        for (int s = 0; s < 6; ++s) o[s] = lg[s] * inv;
    }
}

// ------------- fused = RMSNorm(sum ws*branch) * onorm_w; bf16 in/out; wave-per-head
__global__ __launch_bounds__(256) void fuse_k(const ushort_t* __restrict__ f1,
                                              const ushort_t* __restrict__ f3,
                                              const ushort_t* __restrict__ f7,
                                              const ushort_t* __restrict__ f31,
                                              const ushort_t* __restrict__ dl,
                                              const ushort_t* __restrict__ vv,
                                              const float* __restrict__ wts,
                                              const float* __restrict__ onw,
                                              ushort_t* __restrict__ fused) {
    __shared__ float wloc[24];
    const int row = blockIdx.x, t = threadIdx.x;
    if (t < 24) wloc[t] = wts[(size_t)row * 24 + t];
    __syncthreads();
    const int h = t >> 6, lane = t & 63;
    const size_t idx = (size_t)row * 1024 + h * 256 + lane * 4;
    const ushort_t* ptrs[6] = {f1, f3, f7, f31, dl, vv};
    float f0 = 0.f, f1v = 0.f, f2v = 0.f, f3v = 0.f;
#pragma unroll
    for (int br = 0; br < 6; ++br) {
        const float w = wloc[h * 6 + br];
        const ushort4 xb = *(const ushort4*)&ptrs[br][idx];
        f0 += w * bs2f(xb.x);
        f1v += w * bs2f(xb.y);
        f2v += w * bs2f(xb.z);
        f3v += w * bs2f(xb.w);
    }
    float ss = wred(f0 * f0 + f1v * f1v + f2v * f2v + f3v * f3v);
    ss = __shfl(ss, 0);
    const float scale = rsqrtf(ss / 256.f + 1e-5f);
    const float4 ow = *(const float4*)&onw[lane * 4];
    ushort4 p;
    p.x = f2bs(f0 * scale * ow.x);
    p.y = f2bs(f1v * scale * ow.y);
    p.z = f2bs(f2v * scale * ow.z);
    p.w = f2bs(f3v * scale * ow.w);
    *(ushort4*)&fused[idx] = p;
}

// ================================================================ launch
extern "C" void kernel_launch(void* const* d_in, const int* in_sizes, int n_in,
                              void* d_out, int out_size, void* d_ws, size_t ws_size,
                              hipStream_t stream) {
    const float* hs   = (const float*)d_in[0];
    const float* q_w  = (const float*)d_in[1];
    const float* k_w  = (const float*)d_in[2];
    const float* v_w  = (const float*)d_in[3];
    const float* b_w  = (const float*)d_in[4];
    const float* qc_w = (const float*)d_in[5];
    const float* kc_w = (const float*)d_in[6];
    const float* vc_w = (const float*)d_in[7];
    const float* f1w  = (const float*)d_in[8];
    const float* f3w  = (const float*)d_in[9];
    const float* f7w  = (const float*)d_in[10];
    const float* f31w = (const float*)d_in[11];
    const float* w1   = (const float*)d_in[12];
    const float* b1   = (const float*)d_in[13];
    const float* w2   = (const float*)d_in[14];
    const float* b2   = (const float*)d_in[15];
    const float* glt  = (const float*)d_in[16];
    const float* onw  = (const float*)d_in[17];
    const float* o_w  = (const float*)d_in[18];
    float* out = (float*)d_out;

    const size_t SZ = (size_t)B_ * L_ * D_;  // 4,194,304
    float* qlin = (float*)d_ws;       // qkv[4096][3072] spans 3*SZ; f1 bf16 after scan
    float* klin = qlin + SZ;          // ktfr+qfr bf16 [prep2..scan]; f3 bf16 after
    float* vlin = klin + SZ;          // f7 bf16 after scan
    float* qbuf = vlin + SZ;          // gin_bf (bf16)
    float* kbuf = qbuf + SZ;          // kbf bf16 [conv..prep2]; hgate_bf + fused_bf after
    float* vbuf = kbuf + SZ;          // v bf16
    float* f31b = vbuf + SZ;          // qwT/kwT/vwT early; qbf bf16 [conv..prep2]; f31 after
    float* wb   = f31b + SZ;          // wfr bf16 [prep2..scan]; w1T after scan
    float* ub   = wb + SZ;            // ufr fp32 [prep2..scan]
    float* dlt  = ub + SZ;            // hs_bf early; dlt bf16 [scan..fuse]
    float* beta = dlt + SZ;
    float* attn = beta + (size_t)B_ * L_ * H_;   // atfr bf16
    float* wts = attn + (size_t)B_ * H_ * NC * 1024;
    float* qkv = qlin;  // [4096][3072]

    // bf16 aliases
    ushort_t* hs_bf = (ushort_t*)dlt;
    ushort_t* dlt_bf = (ushort_t*)dlt;
    ushort_t* qwT = (ushort_t*)f31b;
    ushort_t* kwT = (ushort_t*)f31b + 1048576;
    ushort_t* vwT = (ushort_t*)f31b + 2097152;
    ushort_t* qbf = (ushort_t*)f31b + 3145728;
    ushort_t* kbf = (ushort_t*)kbuf;
    ushort_t* vbf = (ushort_t*)vbuf;
    ushort_t* gin_bf = (ushort_t*)qbuf;
    ushort_t* w1T = (ushort_t*)(wb + 2359296);
    ushort_t* owT = (ushort_t*)(wts + 98304);
    ushort_t* hgate_bf = (ushort_t*)kbuf;
    ushort_t* fused_bf = (ushort_t*)kbuf + SZ;
    ushort_t* ktfr = (ushort_t*)klin;
    ushort_t* qfr = (ushort_t*)klin + SZ;
    ushort_t* wfr = (ushort_t*)wb;
    float* ufr = ub;
    ushort_t* atfr = (ushort_t*)attn;
    ushort_t* f1bf = (ushort_t*)qlin;
    ushort_t* f3bf = (ushort_t*)klin;
    ushort_t* f7bf = (ushort_t*)vlin;
    ushort_t* f31bf = (ushort_t*)f31b;

    const int M = B_ * L_;  // 4096

    // weight transposes (q,k,v,o) + beta/gin/hs_bf
    tcast4_k<<<dim3(32, 32, 4), 256, 0, stream>>>(q_w, k_w, v_w, o_w, qwT, kwT, vwT, owT);
    beta_k<<<M, 64, 0, stream>>>(hs, b_w, beta, gin_bf, hs_bf);
    // fused q|k|v projection: qkv[M][3072]
    gemm_bf<0, float><<<dim3(24, 32), 256, 0, stream>>>(hs_bf, qwT, nullptr, qkv, M, 3072, 1024);
    // fused conv+silu(+l2norm) -> bf16
    convql_k<1><<<512, 256, 0, stream>>>(qkv + 0,    qc_w, qbf);
    convql_k<1><<<512, 256, 0, stream>>>(qkv + 1024, kc_w, kbf);
    convql_k<0><<<512, 256, 0, stream>>>(qkv + 2048, vc_w, vbf);
    // chunkwise delta rule
    prep2_k<<<B_ * H_ * NC, 256, 0, stream>>>(qbf, kbf, vbf, beta, qfr, wfr, ufr, atfr, ktfr);
    scan5_k<<<128, 256, 0, stream>>>(qfr, wfr, ufr, atfr, ktfr, dlt_bf);
    // fused FIR branches (bf16)
    fir_k<<<512, 256, 0, stream>>>(vbf, f1w, f3w, f7w, f31w, f1bf, f3bf, f7bf, f31bf);
    // gate
    stats_k<<<M, 256, 0, stream>>>(f1bf, f3bf, f7bf, f31bf, dlt_bf, vbf, gin_bf);
    tcast_k<<<dim3(32, 35), 256, 0, stream>>>(w1, w1T, 1120, 1024);
    gemm_bf<1, ushort_t><<<dim3(8, 32), 256, 0, stream>>>(gin_bf, w1T, b1, hgate_bf,
                                                          M, 1024, 1120);
    wts_k<<<M, 256, 0, stream>>>(hgate_bf, w2, b2, glt, wts);
    fuse_k<<<M, 256, 0, stream>>>(f1bf, f3bf, f7bf, f31bf, dlt_bf, vbf, wts, onw, fused_bf);
    // output projection
    gemm_bf<0, float><<<dim3(8, 32), 256, 0, stream>>>(fused_bf, owT, nullptr, out,
                                                       M, 1024, 1024);
}